// Round 3
// baseline (782.178 us; speedup 1.0000x reference)
//
#include <hip/hip_runtime.h>

#define N_H   5000
#define N_O   15000
#define N_TOT 20000
#define DD    1024
#define E_HH  20000
#define E_OO  40000
#define E_HO  40000
#define E_TOT 100000

typedef unsigned short u16;
typedef unsigned int u32;
typedef __attribute__((ext_vector_type(8))) short short8;
typedef __attribute__((ext_vector_type(4))) float f32x4;
typedef const __attribute__((address_space(1))) u32 gas_u32;
typedef __attribute__((address_space(3))) u32 las_u32;

__device__ __forceinline__ float bf2f(u16 u) {
    union { unsigned int i; float f; } v; v.i = ((unsigned int)u) << 16; return v.f;
}
__device__ __forceinline__ u16 f2bf(float f) {
    union { float f; unsigned int i; } v; v.f = f;
    unsigned int u = v.i;
    return (u16)((u + 0x7FFFu + ((u >> 16) & 1u)) >> 16);
}

// ---------------- fp32 -> bf16 cast (8 elems/thread) ----------------------------
__global__ void cast_bf(const float* __restrict__ in, u16* __restrict__ out) {
    size_t i = ((size_t)blockIdx.x * 256 + threadIdx.x) * 8;
    float4 a = *(const float4*)(in + i);
    float4 b = *(const float4*)(in + i + 4);
    u16 o[8] = {f2bf(a.x), f2bf(a.y), f2bf(a.z), f2bf(a.w),
                f2bf(b.x), f2bf(b.y), f2bf(b.z), f2bf(b.w)};
    *(uint4*)(out + i) = *(const uint4*)o;
}

// ------- W fp32 [2048,1024] -> bf16 Wt[n][k]: top half (k<1024) to dstT, bottom to dstB
__global__ void transpose_w(const float* __restrict__ W, u16* __restrict__ dstT,
                            u16* __restrict__ dstB, int ld) {
    __shared__ float tile[32][33];
    int half = blockIdx.z;
    int bk = blockIdx.x, bn = blockIdx.y;
    int tx = threadIdx.x & 31, ty = threadIdx.x >> 5;   // ty 0..7
#pragma unroll
    for (int yy = 0; yy < 4; yy++) {
        int k = half * 1024 + bk * 32 + ty + yy * 8;
        int n = bn * 32 + tx;
        tile[ty + yy * 8][tx] = W[(size_t)k * 1024 + n];
    }
    __syncthreads();
    u16* dst = half ? dstB : dstT;
#pragma unroll
    for (int yy = 0; yy < 4; yy++) {
        int n = bn * 32 + ty + yy * 8;
        int k = bk * 32 + tx;
        dst[(size_t)n * ld + k] = f2bf(tile[tx][ty + yy * 8]);
    }
}

// ---------------- GEMM: C[M,N] = act(A[M,Kt] @ Bt^T + bias) ---------------------
// A bf16, row stride 1024; A0 covers k<1024, A1 covers k in [1024,2048).
// Bt bf16 [N][Kt], row stride ldb. C: fp32 (c_fp32) or bf16, row stride ldc.
// 1-D grid of nbm*nbn blocks, bn fastest (L2 reuse of A across column tiles).
// Staging via global_load_lds width-16 (m97 structure): LDS tile is contiguous
// [128][64] bf16 (16 KB); wave w & iter t own 1 KB chunk (8 rows), lane i feeds
// row chunk*8+i/8, elem col (i&7)*8.
__launch_bounds__(256)
__global__ void gemm_bt(const u16* __restrict__ A0, const u16* __restrict__ A1,
                        const u16* __restrict__ Bt, int ldb,
                        const float* __restrict__ bias,
                        void* __restrict__ Cp, int ldc, int M, int Kt,
                        int relu, int c_fp32, int nbn) {
    __shared__ u16 lA[128][64];
    __shared__ u16 lB[128][64];
    int bid = blockIdx.x;
    int bm = bid / nbn, bn = bid % nbn;
    int t = threadIdx.x;
    int wave = t >> 6, lane = t & 63;
    int wr = wave >> 1, wc = wave & 1;   // 2x2 wave grid, 64x64 each
    int lm = lane & 15, q = lane >> 4;
    f32x4 acc[4][4] = {};
    int srow = lane >> 3;                // 0..7 within chunk
    int scol = (lane & 7) * 8;           // element col within 64-wide K slab

    for (int k0 = 0; k0 < Kt; k0 += 64) {
        const u16* Asrc = (k0 < 1024) ? A0 : A1;
        int kk = k0 & 1023;
#pragma unroll
        for (int it = 0; it < 4; it++) {
            int chunk = wave * 4 + it;           // 0..15
            int row = chunk * 8 + srow;          // tile row this lane feeds
            int gr = bm * 128 + row; if (gr >= M) gr = M - 1;
            const u16* ga = Asrc + (size_t)gr * 1024 + kk + scol;
            __builtin_amdgcn_global_load_lds((gas_u32*)ga, (las_u32*)&lA[chunk * 8][0], 16, 0, 0);
            const u16* gb = Bt + (size_t)(bn * 128 + row) * ldb + k0 + scol;
            __builtin_amdgcn_global_load_lds((gas_u32*)gb, (las_u32*)&lB[chunk * 8][0], 16, 0, 0);
        }
        __syncthreads();
#pragma unroll
        for (int ks = 0; ks < 64; ks += 32) {
            short8 af[4], bfr[4];
#pragma unroll
            for (int i = 0; i < 4; i++)
                af[i] = *(const short8*)&lA[wr * 64 + i * 16 + lm][ks + q * 8];
#pragma unroll
            for (int j = 0; j < 4; j++)
                bfr[j] = *(const short8*)&lB[wc * 64 + j * 16 + lm][ks + q * 8];
#pragma unroll
            for (int i = 0; i < 4; i++)
#pragma unroll
                for (int j = 0; j < 4; j++)
                    acc[i][j] = __builtin_amdgcn_mfma_f32_16x16x32_bf16(af[i], bfr[j], acc[i][j], 0, 0, 0);
        }
        __syncthreads();
    }
    // D layout per 16x16 tile: row = q*4+r, col = lm
#pragma unroll
    for (int j = 0; j < 4; j++) {
        int col = bn * 128 + wc * 64 + j * 16 + lm;
        float bv = bias ? bias[col] : 0.0f;
#pragma unroll
        for (int i = 0; i < 4; i++) {
            int row0 = bm * 128 + wr * 64 + i * 16 + q * 4;
#pragma unroll
            for (int r = 0; r < 4; r++) {
                int row = row0 + r;
                if (row < M) {
                    float v = acc[i][j][r] + bv;
                    if (relu) v = fmaxf(v, 0.0f);
                    if (c_fp32) ((float*)Cp)[(size_t)row * ldc + col] = v;
                    else        ((u16*)Cp)[(size_t)row * ldc + col] = f2bf(v);
                }
            }
        }
    }
}

// ---------------- concat edge index arrays --------------------------------------
__global__ void cat_edges(const int* __restrict__ shh, const int* __restrict__ dhh,
                          const int* __restrict__ soo, const int* __restrict__ doo,
                          const int* __restrict__ sho, const int* __restrict__ dho,
                          int* __restrict__ src_all, int* __restrict__ dst_all) {
    int e = blockIdx.x * 256 + threadIdx.x;
    if (e >= E_TOT) return;
    int s, d;
    if (e < E_HH)              { s = shh[e];               d = dhh[e]; }
    else if (e < E_HH + E_OO)  { s = soo[e - E_HH];        d = doo[e - E_HH]; }
    else                       { s = sho[e - E_HH - E_OO]; d = dho[e - E_HH - E_OO]; }
    src_all[e] = s; dst_all[e] = d;
}

// --------- per-edge logit: a = ReLU(u[s]+v[d]+b) . W_att + b_att ----------------
// proj_h[m][0:1024]=u_hh, [1024:2048]=v_hh, [2048:3072]=u_ho   (m = h node)
// proj_o[m][0:1024]=u_oo, [1024:2048]=v_oo, [2048:3072]=v_ho   (m = o node - N_H)
__global__ void edge_att(const u16* __restrict__ proj_h, const u16* __restrict__ proj_o,
                         const float* __restrict__ b_hh, const float* __restrict__ b_oo,
                         const float* __restrict__ b_ho, const float* __restrict__ W_att,
                         const float* __restrict__ b_att,
                         const int* __restrict__ src_all, const int* __restrict__ dst_all,
                         float* __restrict__ a_out) {
    int e = blockIdx.x * 4 + (threadIdx.x >> 6);
    int lane = threadIdx.x & 63;
    if (e >= E_TOT) return;
    int s = src_all[e], d = dst_all[e];
    const u16 *u, *v; const float* b;
    if (e < E_HH) {
        u = proj_h + (size_t)s * 3072;
        v = proj_h + (size_t)d * 3072 + 1024;
        b = b_hh;
    } else if (e < E_HH + E_OO) {
        u = proj_o + (size_t)(s - N_H) * 3072;
        v = proj_o + (size_t)(d - N_H) * 3072 + 1024;
        b = b_oo;
    } else {
        u = proj_h + (size_t)s * 3072 + 2048;
        v = proj_o + (size_t)(d - N_H) * 3072 + 2048;
        b = b_ho;
    }
    float acc = 0.f;
#pragma unroll
    for (int c = 0; c < 2; c++) {
        int off = lane * 16 + c * 8;
        uint4 uu = *(const uint4*)(u + off);
        uint4 vv = *(const uint4*)(v + off);
        float4 b0 = *(const float4*)(b + off);
        float4 b1 = *(const float4*)(b + off + 4);
        float4 w0 = *(const float4*)(W_att + off);
        float4 w1 = *(const float4*)(W_att + off + 4);
        const u16* pu = (const u16*)&uu;
        const u16* pv = (const u16*)&vv;
        float bb[8] = {b0.x, b0.y, b0.z, b0.w, b1.x, b1.y, b1.z, b1.w};
        float ww[8] = {w0.x, w0.y, w0.z, w0.w, w1.x, w1.y, w1.z, w1.w};
#pragma unroll
        for (int i = 0; i < 8; i++) {
            float tv = bf2f(pu[i]) + bf2f(pv[i]) + bb[i];
            tv = fmaxf(tv, 0.f);
            acc += tv * ww[i];
        }
    }
#pragma unroll
    for (int o = 32; o > 0; o >>= 1) acc += __shfl_down(acc, o);
    if (lane == 0) a_out[e] = acc + b_att[0];
}

// ---------------- CSR build -----------------------------------------------------
__global__ void deg_count(const int* __restrict__ dst_all, int* __restrict__ deg) {
    int e = blockIdx.x * 256 + threadIdx.x;
    if (e < E_TOT) atomicAdd(&deg[dst_all[e]], 1);
}

__global__ void scan_deg(const int* __restrict__ deg, int* __restrict__ indptr) {
    __shared__ int sums[1024];
    int t = threadIdx.x;
    const int CH = 20;                       // 1024*20 >= 20000
    int beg = t * CH, end = beg + CH;
    if (end > N_TOT) end = N_TOT;
    if (beg > N_TOT) beg = N_TOT;
    int s = 0;
    for (int i = beg; i < end; i++) s += deg[i];
    sums[t] = s;
    __syncthreads();
    for (int off = 1; off < 1024; off <<= 1) {
        int v = sums[t];
        int add = (t >= off) ? sums[t - off] : 0;
        __syncthreads();
        sums[t] = v + add;
        __syncthreads();
    }
    int run = (t == 0) ? 0 : sums[t - 1];
    for (int i = beg; i < end; i++) { indptr[i] = run; run += deg[i]; }
    if (t == 1023) indptr[N_TOT] = sums[1023];
}

__global__ void fill_csr(const int* __restrict__ dst_all, const int* __restrict__ indptr,
                         int* __restrict__ cursor, int* __restrict__ edge_ids) {
    int e = blockIdx.x * 256 + threadIdx.x;
    if (e < E_TOT) {
        int d = dst_all[e];
        int pos = atomicAdd(&cursor[d], 1);
        edge_ids[indptr[d] + pos] = e;
    }
}

// ---------------- per-dst softmax + weighted aggregation of nf_bf[src] ----------
#define MAXDEG 1024
__global__ void soft_z(const float* __restrict__ a, const int* __restrict__ indptr,
                       const int* __restrict__ edge_ids, const int* __restrict__ src_all,
                       const u16* __restrict__ nf, u16* __restrict__ z) {
    __shared__ float s_a[MAXDEG];
    __shared__ int   s_src[MAXDEG];
    __shared__ float s_inv;
    int node = blockIdx.x;
    int t = threadIdx.x;
    int beg = indptr[node], end = indptr[node + 1];
    int deg = end - beg; if (deg > MAXDEG) deg = MAXDEG;
    if (t < 64) {
        float m = -1e30f;
        for (int i = t; i < deg; i += 64) {
            int eid = edge_ids[beg + i];
            float av = a[eid];
            s_a[i] = av;
            s_src[i] = src_all[eid];
            if (av > m) m = av;
        }
        for (int o = 32; o > 0; o >>= 1) m = fmaxf(m, __shfl_down(m, o));
        m = __shfl(m, 0);
        float ssum = 0.f;
        for (int i = t; i < deg; i += 64) {
            float ex = __expf(s_a[i] - m);
            s_a[i] = ex;
            ssum += ex;
        }
        for (int o = 32; o > 0; o >>= 1) ssum += __shfl_down(ssum, o);
        if (t == 0) s_inv = (ssum > 0.f) ? 1.0f / ssum : 0.f;
    }
    __syncthreads();
    float a0 = 0.f, a1 = 0.f, a2 = 0.f, a3 = 0.f;
    int base = t * 4;
    float inv = s_inv;
    for (int i = 0; i < deg; i++) {
        float al = s_a[i] * inv;
        const u16* row = nf + (size_t)s_src[i] * DD + base;
        uint2 p = *(const uint2*)row;
        const u16* pp = (const u16*)&p;
        a0 += al * bf2f(pp[0]); a1 += al * bf2f(pp[1]);
        a2 += al * bf2f(pp[2]); a3 += al * bf2f(pp[3]);
    }
    uint2 ov;
    u16* po = (u16*)&ov;
    po[0] = f2bf(a0); po[1] = f2bf(a1); po[2] = f2bf(a2); po[3] = f2bf(a3);
    *(uint2*)(z + (size_t)node * DD + base) = ov;
}

// ---------------- launch --------------------------------------------------------
extern "C" void kernel_launch(void* const* d_in, const int* in_sizes, int n_in,
                              void* d_out, int out_size, void* d_ws, size_t ws_size,
                              hipStream_t stream) {
    const float* nf   = (const float*)d_in[0];
    const int* shh    = (const int*)d_in[1];
    const int* dhh    = (const int*)d_in[2];
    const int* soo    = (const int*)d_in[3];
    const int* doo    = (const int*)d_in[4];
    const int* sho    = (const int*)d_in[5];
    const int* dho    = (const int*)d_in[6];
    const float* W_hh = (const float*)d_in[7];
    const float* b_hh = (const float*)d_in[8];
    const float* W_oo = (const float*)d_in[9];
    const float* b_oo = (const float*)d_in[10];
    const float* W_ho = (const float*)d_in[11];
    const float* b_ho = (const float*)d_in[12];
    const float* W_att= (const float*)d_in[13];
    const float* b_att= (const float*)d_in[14];
    const float* W_hn = (const float*)d_in[15];
    const float* b_hn = (const float*)d_in[16];
    const float* W_on = (const float*)d_in[17];
    const float* b_on = (const float*)d_in[18];
    float* out = (float*)d_out;

    char* ws = (char*)d_ws;
    size_t off = 0;
    auto alloc = [&](size_t bytes) -> char* {
        char* p = ws + off;
        off += (bytes + 255) & ~(size_t)255;
        return p;
    };
    u16* nf_bf = (u16*)alloc((size_t)N_TOT * DD * 2);          // 41.9 MB
    u16* Bt_h  = (u16*)alloc((size_t)3072 * 1024 * 2);         // 6.3 MB
    u16* Bt_o  = (u16*)alloc((size_t)3072 * 1024 * 2);
    u16* Bt_hn = (u16*)alloc((size_t)1024 * 2048 * 2);         // 4.2 MB
    u16* Bt_on = (u16*)alloc((size_t)1024 * 2048 * 2);
    u16* proj_h = (u16*)alloc((size_t)N_H * 3072 * 2);         // 30.7 MB
    u16* proj_o = (u16*)alloc((size_t)N_O * 3072 * 2);         // 92.2 MB
    u16* z_bf   = proj_h;   // aliases proj (dead after edge_att); 41.9 <= 122.9 MB
    float* a_log  = (float*)alloc(E_TOT * 4);
    int* src_all  = (int*)alloc(E_TOT * 4);
    int* dst_all  = (int*)alloc(E_TOT * 4);
    int* deg      = (int*)alloc(2 * N_TOT * 4);
    int* cursor   = deg + N_TOT;
    int* indptr   = (int*)alloc((N_TOT + 1) * 4);
    int* edge_ids = (int*)alloc(E_TOT * 4);
    (void)ws_size; (void)in_sizes; (void)n_in; (void)out_size;

    // casts + transposes
    cast_bf<<<(N_TOT * DD) / (256 * 8), 256, 0, stream>>>(nf, nf_bf);
    dim3 tgrid(32, 32, 2);
    transpose_w<<<tgrid, 256, 0, stream>>>(W_hh, Bt_h,                       Bt_h + (size_t)1024 * 1024, 1024);
    transpose_w<<<tgrid, 256, 0, stream>>>(W_oo, Bt_o,                       Bt_o + (size_t)1024 * 1024, 1024);
    transpose_w<<<tgrid, 256, 0, stream>>>(W_ho, Bt_h + (size_t)2048 * 1024, Bt_o + (size_t)2048 * 1024, 1024);
    transpose_w<<<tgrid, 256, 0, stream>>>(W_hn, Bt_hn,                      Bt_hn + 1024, 2048);
    transpose_w<<<tgrid, 256, 0, stream>>>(W_on, Bt_on,                      Bt_on + 1024, 2048);

    cat_edges<<<(E_TOT + 255) / 256, 256, 0, stream>>>(shh, dhh, soo, doo, sho, dho, src_all, dst_all);
    hipMemsetAsync(deg, 0, 2 * N_TOT * 4, stream);

    const u16* nf_bf_o = nf_bf + (size_t)N_H * DD;
    // projections: proj_h [5000,3072], proj_o [15000,3072]; 1-D grid, bn fastest
    int nbm_h = (N_H + 127) / 128, nbm_o = (N_O + 127) / 128;
    gemm_bt<<<nbm_h * 24, 256, 0, stream>>>(nf_bf,   nullptr, Bt_h, 1024, nullptr, proj_h, 3072, N_H, 1024, 0, 0, 24);
    gemm_bt<<<nbm_o * 24, 256, 0, stream>>>(nf_bf_o, nullptr, Bt_o, 1024, nullptr, proj_o, 3072, N_O, 1024, 0, 0, 24);

    edge_att<<<(E_TOT + 3) / 4, 256, 0, stream>>>(proj_h, proj_o, b_hh, b_oo, b_ho,
                                                  W_att, b_att, src_all, dst_all, a_log);

    deg_count<<<(E_TOT + 255) / 256, 256, 0, stream>>>(dst_all, deg);
    scan_deg<<<1, 1024, 0, stream>>>(deg, indptr);
    fill_csr<<<(E_TOT + 255) / 256, 256, 0, stream>>>(dst_all, indptr, cursor, edge_ids);

    soft_z<<<N_TOT, 256, 0, stream>>>(a_log, indptr, edge_ids, src_all, nf_bf, z_bf);

    // node apply: out = relu([nf | z] @ W) fp32
    gemm_bt<<<nbm_h * 8, 256, 0, stream>>>(nf_bf,   z_bf,                    Bt_hn, 2048, b_hn, out, 1024, N_H, 2048, 1, 1, 8);
    gemm_bt<<<nbm_o * 8, 256, 0, stream>>>(nf_bf_o, z_bf + (size_t)N_H * DD, Bt_on, 2048, b_on, out + (size_t)N_H * DD, 1024, N_O, 2048, 1, 1, 8);
}

// Round 4
// 715.365 us; speedup vs baseline: 1.0934x; 1.0934x over previous
//
#include <hip/hip_runtime.h>

#define N_H   5000
#define N_O   15000
#define N_TOT 20000
#define DD    1024
#define E_HH  20000
#define E_OO  40000
#define E_HO  40000
#define E_TOT 100000

typedef unsigned short u16;
typedef unsigned int u32;
typedef __attribute__((ext_vector_type(8))) short short8;
typedef __attribute__((ext_vector_type(4))) float f32x4;
typedef const __attribute__((address_space(1))) u32 gas_u32;
typedef __attribute__((address_space(3))) u32 las_u32;

__device__ __forceinline__ float bf2f(u16 u) {
    union { unsigned int i; float f; } v; v.i = ((unsigned int)u) << 16; return v.f;
}
__device__ __forceinline__ u16 f2bf(float f) {
    union { float f; unsigned int i; } v; v.f = f;
    unsigned int u = v.i;
    return (u16)((u + 0x7FFFu + ((u >> 16) & 1u)) >> 16);
}

// ---------------- fp32 -> bf16 cast (8 elems/thread) ----------------------------
__global__ void cast_bf(const float* __restrict__ in, u16* __restrict__ out) {
    size_t i = ((size_t)blockIdx.x * 256 + threadIdx.x) * 8;
    float4 a = *(const float4*)(in + i);
    float4 b = *(const float4*)(in + i + 4);
    u16 o[8] = {f2bf(a.x), f2bf(a.y), f2bf(a.z), f2bf(a.w),
                f2bf(b.x), f2bf(b.y), f2bf(b.z), f2bf(b.w)};
    *(uint4*)(out + i) = *(const uint4*)o;
}

// ------- W fp32 [2048,1024] -> bf16 Wt[n][k]: top half (k<1024) to dstT, bottom to dstB
__global__ void transpose_w(const float* __restrict__ W, u16* __restrict__ dstT,
                            u16* __restrict__ dstB, int ld) {
    __shared__ float tile[32][33];
    int half = blockIdx.z;
    int bk = blockIdx.x, bn = blockIdx.y;
    int tx = threadIdx.x & 31, ty = threadIdx.x >> 5;   // ty 0..7
#pragma unroll
    for (int yy = 0; yy < 4; yy++) {
        int k = half * 1024 + bk * 32 + ty + yy * 8;
        int n = bn * 32 + tx;
        tile[ty + yy * 8][tx] = W[(size_t)k * 1024 + n];
    }
    __syncthreads();
    u16* dst = half ? dstB : dstT;
#pragma unroll
    for (int yy = 0; yy < 4; yy++) {
        int n = bn * 32 + ty + yy * 8;
        int k = bk * 32 + tx;
        dst[(size_t)n * ld + k] = f2bf(tile[tx][ty + yy * 8]);
    }
}

// ---------------- GEMM: C[M,N] = act(A[M,Kt] @ Bt^T + bias) ---------------------
// A bf16, row stride 1024; A0 covers k<1024, A1 covers k in [1024,2048).
// Bt bf16 [N][Kt], row stride ldb. C: fp32 (c_fp32) or bf16, row stride ldc.
// 1-D grid, bn fastest (L2 reuse of A across column tiles).
// global_load_lds width-16 staging into XOR-swizzled [128][64] tile:
//   physical 16B-chunk p of row r holds logical chunk p ^ (r&7).
// Staging: lane i fetches logical chunk (i&7)^(i>>3) of row chunk*8+(i>>3),
// lands at LDS base + i*16 (wave-uniform base, lane-contiguous -> HW rule ok).
// Fragment reads: physical chunk = ((ks>>3)+q) ^ (lm&7) -> 8 words/bank = b128 floor.
__launch_bounds__(256)
__global__ void gemm_bt(const u16* __restrict__ A0, const u16* __restrict__ A1,
                        const u16* __restrict__ Bt, int ldb,
                        const float* __restrict__ bias,
                        void* __restrict__ Cp, int ldc, int M, int Kt,
                        int relu, int c_fp32, int nbn) {
    __shared__ u16 lA[128][64];
    __shared__ u16 lB[128][64];
    int bid = blockIdx.x;
    int bm = bid / nbn, bn = bid % nbn;
    int t = threadIdx.x;
    int wave = t >> 6, lane = t & 63;
    int wr = wave >> 1, wc = wave & 1;   // 2x2 wave grid, 64x64 each
    int lm = lane & 15, q = lane >> 4;
    f32x4 acc[4][4] = {};
    int srow = lane >> 3;                       // 0..7 within chunk
    int scol = ((lane & 7) ^ srow) * 8;         // swizzled source chunk

    for (int k0 = 0; k0 < Kt; k0 += 64) {
        const u16* Asrc = (k0 < 1024) ? A0 : A1;
        int kk = k0 & 1023;
#pragma unroll
        for (int it = 0; it < 4; it++) {
            int chunk = wave * 4 + it;           // 0..15
            int row = chunk * 8 + srow;          // tile row this lane feeds
            int gr = bm * 128 + row; if (gr >= M) gr = M - 1;
            const u16* ga = Asrc + (size_t)gr * 1024 + kk + scol;
            __builtin_amdgcn_global_load_lds((gas_u32*)ga, (las_u32*)&lA[chunk * 8][0], 16, 0, 0);
            const u16* gb = Bt + (size_t)(bn * 128 + row) * ldb + k0 + scol;
            __builtin_amdgcn_global_load_lds((gas_u32*)gb, (las_u32*)&lB[chunk * 8][0], 16, 0, 0);
        }
        __syncthreads();
#pragma unroll
        for (int ks = 0; ks < 64; ks += 32) {
            short8 af[4], bfr[4];
            int pc = (((ks >> 3) + q) ^ (lm & 7)) * 8;   // swizzled physical col
#pragma unroll
            for (int i = 0; i < 4; i++)
                af[i] = *(const short8*)&lA[wr * 64 + i * 16 + lm][pc];
#pragma unroll
            for (int j = 0; j < 4; j++)
                bfr[j] = *(const short8*)&lB[wc * 64 + j * 16 + lm][pc];
#pragma unroll
            for (int i = 0; i < 4; i++)
#pragma unroll
                for (int j = 0; j < 4; j++)
                    acc[i][j] = __builtin_amdgcn_mfma_f32_16x16x32_bf16(af[i], bfr[j], acc[i][j], 0, 0, 0);
        }
        __syncthreads();
    }
    // D layout per 16x16 tile: row = q*4+r, col = lm
#pragma unroll
    for (int j = 0; j < 4; j++) {
        int col = bn * 128 + wc * 64 + j * 16 + lm;
        float bv = bias ? bias[col] : 0.0f;
#pragma unroll
        for (int i = 0; i < 4; i++) {
            int row0 = bm * 128 + wr * 64 + i * 16 + q * 4;
#pragma unroll
            for (int r = 0; r < 4; r++) {
                int row = row0 + r;
                if (row < M) {
                    float v = acc[i][j][r] + bv;
                    if (relu) v = fmaxf(v, 0.0f);
                    if (c_fp32) ((float*)Cp)[(size_t)row * ldc + col] = v;
                    else        ((u16*)Cp)[(size_t)row * ldc + col] = f2bf(v);
                }
            }
        }
    }
}

// ---------------- concat edge index arrays --------------------------------------
__global__ void cat_edges(const int* __restrict__ shh, const int* __restrict__ dhh,
                          const int* __restrict__ soo, const int* __restrict__ doo,
                          const int* __restrict__ sho, const int* __restrict__ dho,
                          int* __restrict__ src_all, int* __restrict__ dst_all) {
    int e = blockIdx.x * 256 + threadIdx.x;
    if (e >= E_TOT) return;
    int s, d;
    if (e < E_HH)              { s = shh[e];               d = dhh[e]; }
    else if (e < E_HH + E_OO)  { s = soo[e - E_HH];        d = doo[e - E_HH]; }
    else                       { s = sho[e - E_HH - E_OO]; d = dho[e - E_HH - E_OO]; }
    src_all[e] = s; dst_all[e] = d;
}

// --------- per-edge logit: a = ReLU(u[s]+v[d]+b) . W_att + b_att ----------------
// proj_h[m][0:1024]=u_hh, [1024:2048]=v_hh, [2048:3072]=u_ho   (m = h node)
// proj_o[m][0:1024]=u_oo, [1024:2048]=v_oo, [2048:3072]=v_ho   (m = o node - N_H)
__global__ void edge_att(const u16* __restrict__ proj_h, const u16* __restrict__ proj_o,
                         const float* __restrict__ b_hh, const float* __restrict__ b_oo,
                         const float* __restrict__ b_ho, const float* __restrict__ W_att,
                         const float* __restrict__ b_att,
                         const int* __restrict__ src_all, const int* __restrict__ dst_all,
                         float* __restrict__ a_out) {
    int e = blockIdx.x * 4 + (threadIdx.x >> 6);
    int lane = threadIdx.x & 63;
    if (e >= E_TOT) return;
    int s = src_all[e], d = dst_all[e];
    const u16 *u, *v; const float* b;
    if (e < E_HH) {
        u = proj_h + (size_t)s * 3072;
        v = proj_h + (size_t)d * 3072 + 1024;
        b = b_hh;
    } else if (e < E_HH + E_OO) {
        u = proj_o + (size_t)(s - N_H) * 3072;
        v = proj_o + (size_t)(d - N_H) * 3072 + 1024;
        b = b_oo;
    } else {
        u = proj_h + (size_t)s * 3072 + 2048;
        v = proj_o + (size_t)(d - N_H) * 3072 + 2048;
        b = b_ho;
    }
    float acc = 0.f;
#pragma unroll
    for (int c = 0; c < 2; c++) {
        int off = lane * 16 + c * 8;
        uint4 uu = *(const uint4*)(u + off);
        uint4 vv = *(const uint4*)(v + off);
        float4 b0 = *(const float4*)(b + off);
        float4 b1 = *(const float4*)(b + off + 4);
        float4 w0 = *(const float4*)(W_att + off);
        float4 w1 = *(const float4*)(W_att + off + 4);
        const u16* pu = (const u16*)&uu;
        const u16* pv = (const u16*)&vv;
        float bb[8] = {b0.x, b0.y, b0.z, b0.w, b1.x, b1.y, b1.z, b1.w};
        float ww[8] = {w0.x, w0.y, w0.z, w0.w, w1.x, w1.y, w1.z, w1.w};
#pragma unroll
        for (int i = 0; i < 8; i++) {
            float tv = bf2f(pu[i]) + bf2f(pv[i]) + bb[i];
            tv = fmaxf(tv, 0.f);
            acc += tv * ww[i];
        }
    }
#pragma unroll
    for (int o = 32; o > 0; o >>= 1) acc += __shfl_down(acc, o);
    if (lane == 0) a_out[e] = acc + b_att[0];
}

// ---------------- CSR build -----------------------------------------------------
__global__ void deg_count(const int* __restrict__ dst_all, int* __restrict__ deg) {
    int e = blockIdx.x * 256 + threadIdx.x;
    if (e < E_TOT) atomicAdd(&deg[dst_all[e]], 1);
}

__global__ void scan_deg(const int* __restrict__ deg, int* __restrict__ indptr) {
    __shared__ int sums[1024];
    int t = threadIdx.x;
    const int CH = 20;                       // 1024*20 >= 20000
    int beg = t * CH, end = beg + CH;
    if (end > N_TOT) end = N_TOT;
    if (beg > N_TOT) beg = N_TOT;
    int s = 0;
    for (int i = beg; i < end; i++) s += deg[i];
    sums[t] = s;
    __syncthreads();
    for (int off = 1; off < 1024; off <<= 1) {
        int v = sums[t];
        int add = (t >= off) ? sums[t - off] : 0;
        __syncthreads();
        sums[t] = v + add;
        __syncthreads();
    }
    int run = (t == 0) ? 0 : sums[t - 1];
    for (int i = beg; i < end; i++) { indptr[i] = run; run += deg[i]; }
    if (t == 1023) indptr[N_TOT] = sums[1023];
}

__global__ void fill_csr(const int* __restrict__ dst_all, const int* __restrict__ indptr,
                         int* __restrict__ cursor, int* __restrict__ edge_ids) {
    int e = blockIdx.x * 256 + threadIdx.x;
    if (e < E_TOT) {
        int d = dst_all[e];
        int pos = atomicAdd(&cursor[d], 1);
        edge_ids[indptr[d] + pos] = e;
    }
}

// ---------------- per-dst softmax + weighted aggregation of nf_bf[src] ----------
#define MAXDEG 1024
__global__ void soft_z(const float* __restrict__ a, const int* __restrict__ indptr,
                       const int* __restrict__ edge_ids, const int* __restrict__ src_all,
                       const u16* __restrict__ nf, u16* __restrict__ z) {
    __shared__ float s_a[MAXDEG];
    __shared__ int   s_src[MAXDEG];
    __shared__ float s_inv;
    int node = blockIdx.x;
    int t = threadIdx.x;
    int beg = indptr[node], end = indptr[node + 1];
    int deg = end - beg; if (deg > MAXDEG) deg = MAXDEG;
    if (t < 64) {
        float m = -1e30f;
        for (int i = t; i < deg; i += 64) {
            int eid = edge_ids[beg + i];
            float av = a[eid];
            s_a[i] = av;
            s_src[i] = src_all[eid];
            if (av > m) m = av;
        }
        for (int o = 32; o > 0; o >>= 1) m = fmaxf(m, __shfl_down(m, o));
        m = __shfl(m, 0);
        float ssum = 0.f;
        for (int i = t; i < deg; i += 64) {
            float ex = __expf(s_a[i] - m);
            s_a[i] = ex;
            ssum += ex;
        }
        for (int o = 32; o > 0; o >>= 1) ssum += __shfl_down(ssum, o);
        if (t == 0) s_inv = (ssum > 0.f) ? 1.0f / ssum : 0.f;
    }
    __syncthreads();
    float a0 = 0.f, a1 = 0.f, a2 = 0.f, a3 = 0.f;
    int base = t * 4;
    float inv = s_inv;
    for (int i = 0; i < deg; i++) {
        float al = s_a[i] * inv;
        const u16* row = nf + (size_t)s_src[i] * DD + base;
        uint2 p = *(const uint2*)row;
        const u16* pp = (const u16*)&p;
        a0 += al * bf2f(pp[0]); a1 += al * bf2f(pp[1]);
        a2 += al * bf2f(pp[2]); a3 += al * bf2f(pp[3]);
    }
    uint2 ov;
    u16* po = (u16*)&ov;
    po[0] = f2bf(a0); po[1] = f2bf(a1); po[2] = f2bf(a2); po[3] = f2bf(a3);
    *(uint2*)(z + (size_t)node * DD + base) = ov;
}

// ---------------- launch --------------------------------------------------------
extern "C" void kernel_launch(void* const* d_in, const int* in_sizes, int n_in,
                              void* d_out, int out_size, void* d_ws, size_t ws_size,
                              hipStream_t stream) {
    const float* nf   = (const float*)d_in[0];
    const int* shh    = (const int*)d_in[1];
    const int* dhh    = (const int*)d_in[2];
    const int* soo    = (const int*)d_in[3];
    const int* doo    = (const int*)d_in[4];
    const int* sho    = (const int*)d_in[5];
    const int* dho    = (const int*)d_in[6];
    const float* W_hh = (const float*)d_in[7];
    const float* b_hh = (const float*)d_in[8];
    const float* W_oo = (const float*)d_in[9];
    const float* b_oo = (const float*)d_in[10];
    const float* W_ho = (const float*)d_in[11];
    const float* b_ho = (const float*)d_in[12];
    const float* W_att= (const float*)d_in[13];
    const float* b_att= (const float*)d_in[14];
    const float* W_hn = (const float*)d_in[15];
    const float* b_hn = (const float*)d_in[16];
    const float* W_on = (const float*)d_in[17];
    const float* b_on = (const float*)d_in[18];
    float* out = (float*)d_out;

    char* ws = (char*)d_ws;
    size_t off = 0;
    auto alloc = [&](size_t bytes) -> char* {
        char* p = ws + off;
        off += (bytes + 255) & ~(size_t)255;
        return p;
    };
    u16* nf_bf = (u16*)alloc((size_t)N_TOT * DD * 2);          // 41.9 MB
    u16* Bt_h  = (u16*)alloc((size_t)3072 * 1024 * 2);         // 6.3 MB
    u16* Bt_o  = (u16*)alloc((size_t)3072 * 1024 * 2);
    u16* Bt_hn = (u16*)alloc((size_t)1024 * 2048 * 2);         // 4.2 MB
    u16* Bt_on = (u16*)alloc((size_t)1024 * 2048 * 2);
    u16* proj_h = (u16*)alloc((size_t)N_H * 3072 * 2);         // 30.7 MB
    u16* proj_o = (u16*)alloc((size_t)N_O * 3072 * 2);         // 92.2 MB
    u16* z_bf   = proj_h;   // aliases proj (dead after edge_att); 41.9 <= 122.9 MB
    float* a_log  = (float*)alloc(E_TOT * 4);
    int* src_all  = (int*)alloc(E_TOT * 4);
    int* dst_all  = (int*)alloc(E_TOT * 4);
    int* deg      = (int*)alloc(2 * N_TOT * 4);
    int* cursor   = deg + N_TOT;
    int* indptr   = (int*)alloc((N_TOT + 1) * 4);
    int* edge_ids = (int*)alloc(E_TOT * 4);
    (void)ws_size; (void)in_sizes; (void)n_in; (void)out_size;

    // casts + transposes
    cast_bf<<<(N_TOT * DD) / (256 * 8), 256, 0, stream>>>(nf, nf_bf);
    dim3 tgrid(32, 32, 2);
    transpose_w<<<tgrid, 256, 0, stream>>>(W_hh, Bt_h,                       Bt_h + (size_t)1024 * 1024, 1024);
    transpose_w<<<tgrid, 256, 0, stream>>>(W_oo, Bt_o,                       Bt_o + (size_t)1024 * 1024, 1024);
    transpose_w<<<tgrid, 256, 0, stream>>>(W_ho, Bt_h + (size_t)2048 * 1024, Bt_o + (size_t)2048 * 1024, 1024);
    transpose_w<<<tgrid, 256, 0, stream>>>(W_hn, Bt_hn,                      Bt_hn + 1024, 2048);
    transpose_w<<<tgrid, 256, 0, stream>>>(W_on, Bt_on,                      Bt_on + 1024, 2048);

    cat_edges<<<(E_TOT + 255) / 256, 256, 0, stream>>>(shh, dhh, soo, doo, sho, dho, src_all, dst_all);
    hipMemsetAsync(deg, 0, 2 * N_TOT * 4, stream);

    const u16* nf_bf_o = nf_bf + (size_t)N_H * DD;
    // projections: proj_h [5000,3072], proj_o [15000,3072]; 1-D grid, bn fastest
    int nbm_h = (N_H + 127) / 128, nbm_o = (N_O + 127) / 128;
    gemm_bt<<<nbm_h * 24, 256, 0, stream>>>(nf_bf,   nullptr, Bt_h, 1024, nullptr, proj_h, 3072, N_H, 1024, 0, 0, 24);
    gemm_bt<<<nbm_o * 24, 256, 0, stream>>>(nf_bf_o, nullptr, Bt_o, 1024, nullptr, proj_o, 3072, N_O, 1024, 0, 0, 24);

    edge_att<<<(E_TOT + 3) / 4, 256, 0, stream>>>(proj_h, proj_o, b_hh, b_oo, b_ho,
                                                  W_att, b_att, src_all, dst_all, a_log);

    deg_count<<<(E_TOT + 255) / 256, 256, 0, stream>>>(dst_all, deg);
    scan_deg<<<1, 1024, 0, stream>>>(deg, indptr);
    fill_csr<<<(E_TOT + 255) / 256, 256, 0, stream>>>(dst_all, indptr, cursor, edge_ids);

    soft_z<<<N_TOT, 256, 0, stream>>>(a_log, indptr, edge_ids, src_all, nf_bf, z_bf);

    // node apply: out = relu([nf | z] @ W) fp32
    gemm_bt<<<nbm_h * 8, 256, 0, stream>>>(nf_bf,   z_bf,                    Bt_hn, 2048, b_hn, out, 1024, N_H, 2048, 1, 1, 8);
    gemm_bt<<<nbm_o * 8, 256, 0, stream>>>(nf_bf_o, z_bf + (size_t)N_H * DD, Bt_on, 2048, b_on, out + (size_t)N_H * DD, 1024, N_O, 2048, 1, 1, 8);
}